// Round 4
// baseline (299.561 us; speedup 1.0000x reference)
//
#include <hip/hip_runtime.h>

// KANConv2D: out[b,h,w,f] = conv3x3(x,K)[.,f] + exp(-gamma * d[.,f]) + bias[f]
// d = ||patch||^2 + ||c_f||^2 - 2*patch.c_f ; gamma = (N*F)/(2*sum(d))
//
// v4: 3 launches. k_main:
//  - persistent zero-padded bf16 image tile in LDS (4 rows x 68 px x 64 ch),
//    staged ONCE; all 9 (ki,kj) A-views are LDS offsets (v3 idea, kept)
//  - B fragments loaded DIRECTLY from global (bf16 [F][P], L1/L2-resident):
//    no LDS B, no K-loop barriers, compiler free to pipeline loads w/ MFMA
//  - no register prefetch arrays (v3's spill source — WRITE_SIZE 189MB)
//  - ||patch||^2 from LDS tile; conv(fp16)+d(fp16) packed to d_out; in-place final.

#define B_ 32
#define H_ 64
#define W_ 64
#define C_ 64
#define F_ 128
#define P_ 576
#define NPIX (B_*H_*W_)          // 131072
#define NF   (NPIX*F_)           // 16777216

typedef __bf16  bf16x8 __attribute__((ext_vector_type(8)));
typedef float   f32x4  __attribute__((ext_vector_type(4)));

union HU { _Float16 h; ushort u; };
union FU { float f; uint u; };

__device__ __forceinline__ ushort f2bf(float f) {
    FU v; v.f = f;
    return (ushort)((v.u + 0x7fffu + ((v.u >> 16) & 1u)) >> 16);   // RNE
}
__device__ __forceinline__ uint pk(float a, float b) {
    return (uint)f2bf(a) | ((uint)f2bf(b) << 16);
}
__device__ __forceinline__ ushort f2h(float f) { HU h; h.h = (_Float16)f; return h.u; }
__device__ __forceinline__ float  h2f(ushort u) { HU h; h.u = u; return (float)h.h; }
__device__ __forceinline__ float  bflo(uint u) { FU v; v.u = u << 16; return v.f; }
__device__ __forceinline__ float  bfhi(uint u) { FU v; v.u = u & 0xffff0000u; return v.f; }

// ---------------- P: transpose+convert B mats (blocks 0..287), cn+accum (block 288)
__global__ void k_prep(const float* __restrict__ wgt, const float* __restrict__ ctrl,
                       ushort* __restrict__ Btw, ushort* __restrict__ Btc,
                       float* __restrict__ cn, float* __restrict__ accum) {
    if (blockIdx.x < 288) {
        int e = blockIdx.x * 256 + threadIdx.x;   // < 73728
        int p = e >> 7, f = e & 127;
        Btw[f * P_ + p] = f2bf(wgt[e]);
        Btc[f * P_ + p] = f2bf(ctrl[e]);
    } else if (threadIdx.x < 128) {
        int f = threadIdx.x;
        float s = 0.f;
        for (int p = 0; p < P_; ++p) { float v = ctrl[p * F_ + f]; s += v * v; }
        cn[f] = s;
        if (f == 0) accum[0] = 0.f;
    }
}

// ---------------- D: fused dual implicit GEMM, barrier-free K-loop ----------------
// 512 threads = 8 waves; tile = 128 rows (2 image rows) x 128 F.
// waves 0-3: conv (32 rows each), waves 4-7: dot (32 rows each).
// LDS: lI [4][68][64] bf16 image tile (XOR-swizzled 16B chunks, zero-padded),
//      sArr [4][68] f32, pnAr [128] f32.  36416 B total.
__launch_bounds__(512, 4)
__global__ void k_main(const float* __restrict__ in,
                       const ushort* __restrict__ Btw, const ushort* __restrict__ Btc,
                       const float* __restrict__ bias, const float* __restrict__ cn,
                       uint* __restrict__ out, float* __restrict__ accum) {
    __shared__ __attribute__((aligned(16))) ushort smem[18208];
    ushort* lI   = smem;                           // 17408 ush
    float*  sArr = (float*)(smem + 17408);         // 272 f32 (stride 68)
    float*  pnAr = (float*)(smem + 17408 + 544);   // 128 f32

    const int tid = threadIdx.x;
    const int n0  = blockIdx.x * 128;          // 2 image rows, same image
    const int b   = n0 >> 12;
    const int y0  = (n0 >> 6) & 63;
    const float* inb = in + b * 262144;

    const int w     = tid >> 6, lane = tid & 63;
    const int mat   = w >> 2;                  // 0: conv, 1: dot
    const int mrow0 = (w & 3) * 32;
    const int quad  = lane >> 4, l16 = lane & 15;

    // ---- stage image tile once: 4 rows x 68 px x 8 chunks = 2176 chunks
    #pragma unroll
    for (int p = 0; p < 5; ++p) {
        int g = tid + p * 512;
        if (g < 2176) {
            int row4 = g / 544;                // 544 = 68*8
            int rem  = g - row4 * 544;
            int px = rem >> 3, c = rem & 7;
            int y = y0 + row4 - 1, x = px - 1;
            float4 v0 = make_float4(0.f, 0.f, 0.f, 0.f), v1 = v0;
            if (y >= 0 && y < 64 && x >= 0 && x < 64) {
                const float* sp = inb + y * 4096 + x * 64 + c * 8;
                v0 = *(const float4*)sp;
                v1 = *(const float4*)(sp + 4);
            }
            uint4 o = { pk(v0.x, v0.y), pk(v0.z, v0.w), pk(v1.x, v1.y), pk(v1.z, v1.w) };
            *(uint4*)&lI[(row4 * 68 + px) * 64 + ((c ^ (px & 7)) << 3)] = o;
        }
    }
    __syncthreads();

    // ---- s[row4][px] = channel sqnorm of tile pixel (zero pixels give 0)
    if (tid < 264) {
        int row4 = tid / 66, px = tid - row4 * 66;
        const ushort* base = &lI[(row4 * 68 + px) * 64];
        float s = 0.f;
        #pragma unroll
        for (int j = 0; j < 8; ++j) {
            int jj = (j + px) & 7;             // rotate to spread banks
            uint4 v = *(const uint4*)&base[jj << 3];
            float a0 = bflo(v.x), a1 = bfhi(v.x), a2 = bflo(v.y), a3 = bfhi(v.y);
            float a4 = bflo(v.z), a5 = bfhi(v.z), a6 = bflo(v.w), a7 = bfhi(v.w);
            s += a0*a0 + a1*a1 + a2*a2 + a3*a3 + a4*a4 + a5*a5 + a6*a6 + a7*a7;
        }
        sArr[row4 * 68 + px] = s;
    }
    __syncthreads();

    // ---- pn[r] = 3x3 box sum (zero-padding already in sArr); consumed in epilogue
    if (tid < 128) {
        int yr = tid >> 6, x = tid & 63;
        float a = 0.f;
        #pragma unroll
        for (int dr = 0; dr < 3; ++dr)
            #pragma unroll
            for (int dc = 0; dc < 3; ++dc)
                a += sArr[(yr + dr) * 68 + x + dc];
        pnAr[tid] = a;
    }

    f32x4 acc[2][8];
    #pragma unroll
    for (int mt = 0; mt < 2; ++mt)
        #pragma unroll
        for (int nt = 0; nt < 8; ++nt)
            acc[mt][nt] = (f32x4){0.f, 0.f, 0.f, 0.f};

    const int yrA = mrow0 >> 6;                // image row within tile (0/1)
    const int xbA = mrow0 & 63;                // 0 or 32
    // per-lane B base: element (nt*16+l16)*576 + kc*64 + ks*32 + quad*8
    const ushort* bb = (mat ? Btc : Btw) + l16 * 576 + quad * 8;

    // ---- barrier-free K-loop: A from LDS tile, B straight from L1/L2 ----
    for (int kc = 0; kc < 9; ++kc) {
        const int ki = kc / 3, kj = kc - 3 * ki;
        const int rbase = (yrA + ki) * 68;
        const int px0   = xbA + l16 + kj;
        const int ad0   = (rbase + px0) * 64;
        const int ad1   = ad0 + 16 * 64;       // px0+16: same swizzle key (&7)
        const ushort* bk = bb + kc * 64;

        #pragma unroll
        for (int ks = 0; ks < 2; ++ks) {
            const int c  = ks * 4 + quad;
            const int sw = (c ^ (px0 & 7)) << 3;
            bf16x8 a0 = *(const bf16x8*)&lI[ad0 + sw];
            bf16x8 a1 = *(const bf16x8*)&lI[ad1 + sw];
            #pragma unroll
            for (int nt = 0; nt < 8; ++nt) {
                bf16x8 bq = *(const bf16x8*)(bk + nt * 9216 + ks * 32);
                acc[0][nt] = __builtin_amdgcn_mfma_f32_16x16x32_bf16(a0, bq, acc[0][nt], 0, 0, 0);
                acc[1][nt] = __builtin_amdgcn_mfma_f32_16x16x32_bf16(a1, bq, acc[1][nt], 0, 0, 0);
            }
        }
    }

    // ---- epilogue: C/D layout col=lane&15, row=quad*4+reg [m89/m91]
    // exchange region reuses lI: slot per (wave&3, lane), stride 68 ushorts
    ushort* exch = smem;
    __syncthreads();
    if (mat == 1) {
        float pv[2][4];
        #pragma unroll
        for (int mt = 0; mt < 2; ++mt)
            #pragma unroll
            for (int r = 0; r < 4; ++r)
                pv[mt][r] = pnAr[mrow0 + mt * 16 + quad * 4 + r];
        float cv[8];
        #pragma unroll
        for (int nt = 0; nt < 8; ++nt) cv[nt] = cn[nt * 16 + l16];
        float sum = 0.f;
        ushort* my = exch + ((w & 3) * 64 + lane) * 68;
        #pragma unroll
        for (int mt = 0; mt < 2; ++mt)
            #pragma unroll
            for (int nt = 0; nt < 8; ++nt) {
                float d0 = pv[mt][0] + cv[nt] - 2.f * acc[mt][nt][0];
                float d1 = pv[mt][1] + cv[nt] - 2.f * acc[mt][nt][1];
                float d2 = pv[mt][2] + cv[nt] - 2.f * acc[mt][nt][2];
                float d3 = pv[mt][3] + cv[nt] - 2.f * acc[mt][nt][3];
                sum += d0 + d1 + d2 + d3;
                ushort4 hv = { f2h(d0), f2h(d1), f2h(d2), f2h(d3) };
                *(ushort4*)&my[(mt * 8 + nt) * 4] = hv;
            }
        #pragma unroll
        for (int off = 32; off >= 1; off >>= 1) sum += __shfl_down(sum, off, 64);
        if (lane == 0) atomicAdd(accum, sum);
    }
    __syncthreads();
    if (mat == 0) {
        float bv[8];
        #pragma unroll
        for (int nt = 0; nt < 8; ++nt) bv[nt] = bias[nt * 16 + l16];
        const ushort* my = exch + ((w & 3) * 64 + lane) * 68;
        #pragma unroll
        for (int mt = 0; mt < 2; ++mt) {
            int gmb = n0 + mrow0 + mt * 16 + quad * 4;
            #pragma unroll
            for (int nt = 0; nt < 8; ++nt) {
                int gf = nt * 16 + l16;
                ushort4 hv = *(const ushort4*)&my[(mt * 8 + nt) * 4];
                ushort dd[4] = { hv.x, hv.y, hv.z, hv.w };
                #pragma unroll
                for (int r = 0; r < 4; ++r) {
                    uint pkv = ((uint)dd[r] << 16) | (uint)f2h(acc[mt][nt][r] + bv[nt]);
                    out[(gmb + r) * F_ + gf] = pkv;
                }
            }
        }
    }
}

// ---------------- E: in-place out = conv + exp(-gamma*d) ----------------
__global__ void k_final(uint* __restrict__ out, const float* __restrict__ accum) {
    int i = blockIdx.x * 256 + threadIdx.x;       // handles elems [8i, 8i+8)
    float g = 0.5f * (float)NF / accum[0];        // gamma = 1/(2*mean)
    uint4* p = (uint4*)out;
    uint4 u0 = p[2 * i], u1 = p[2 * i + 1];
    float4 f0, f1;
    f0.x = h2f((ushort)(u0.x & 0xffff)) + __expf(-g * h2f((ushort)(u0.x >> 16)));
    f0.y = h2f((ushort)(u0.y & 0xffff)) + __expf(-g * h2f((ushort)(u0.y >> 16)));
    f0.z = h2f((ushort)(u0.z & 0xffff)) + __expf(-g * h2f((ushort)(u0.z >> 16)));
    f0.w = h2f((ushort)(u0.w & 0xffff)) + __expf(-g * h2f((ushort)(u0.w >> 16)));
    f1.x = h2f((ushort)(u1.x & 0xffff)) + __expf(-g * h2f((ushort)(u1.x >> 16)));
    f1.y = h2f((ushort)(u1.y & 0xffff)) + __expf(-g * h2f((ushort)(u1.y >> 16)));
    f1.z = h2f((ushort)(u1.z & 0xffff)) + __expf(-g * h2f((ushort)(u1.z >> 16)));
    f1.w = h2f((ushort)(u1.w & 0xffff)) + __expf(-g * h2f((ushort)(u1.w >> 16)));
    float4* q = (float4*)out;
    q[2 * i] = f0; q[2 * i + 1] = f1;             // in-place, same bytes
}

extern "C" void kernel_launch(void* const* d_in, const int* in_sizes, int n_in,
                              void* d_out, int out_size, void* d_ws, size_t ws_size,
                              hipStream_t stream) {
    const float* in   = (const float*)d_in[0];   // [32,64,64,64]
    const float* wgt  = (const float*)d_in[1];   // [3,3,64,128]
    const float* bias = (const float*)d_in[2];   // [128]
    const float* ctrl = (const float*)d_in[3];   // [3,3,64,128]
    uint* out = (uint*)d_out;

    // ws: Btw @0 (147456 B) | Btc @147456 | cn @294912 | accum @295424
    char* ws = (char*)d_ws;
    ushort* Btw   = (ushort*)(ws + 0);
    ushort* Btc   = (ushort*)(ws + 147456);
    float*  cn    = (float*) (ws + 294912);
    float*  accum = (float*) (ws + 295424);

    k_prep  <<<289,          256, 0, stream>>>(wgt, ctrl, Btw, Btc, cn, accum);
    k_main  <<<NPIX / 128,   512, 0, stream>>>(in, Btw, Btc, bias, cn, out, accum);
    k_final <<<NF / 8 / 256, 256, 0, stream>>>(out, accum);
}

// Round 5
// 227.906 us; speedup vs baseline: 1.3144x; 1.3144x over previous
//
#include <hip/hip_runtime.h>

// KANConv2D: out[b,h,w,f] = conv3x3(x,K)[.,f] + exp(-gamma * d[.,f]) + bias[f]
// d = ||patch||^2 + ||c_f||^2 - 2*patch.c_f ; gamma = (N*F)/(2*sum(d))
//
// v5: 3 launches.
//  - k_prep writes both B matrices bf16 in MFMA-fragment order
//    [kc][mat][ks][ntg][lane][8] so k_main's B staging is a straight copy.
//  - k_main: 256 thr / 4 waves; wave(mat, fhalf) computes 128M x 64F
//    (acc 128 VGPR; 4x better B amortization than 32Mx128F -> LDS floor ~23us).
//    Persistent zero-padded bf16 image tile (4 rows x 68 px x 64 ch) staged once;
//    per-kc B (32 KB both mats) register-prefetched from L2 into LDS.
//    ||patch||^2 from LDS tile; conv(fp16)+d(fp16) packed to d_out.
//  - k_final: in-place out = conv + exp(-gamma*d).

#define B_ 32
#define H_ 64
#define W_ 64
#define C_ 64
#define F_ 128
#define P_ 576
#define NPIX (B_*H_*W_)          // 131072
#define NF   (NPIX*F_)           // 16777216

typedef __bf16  bf16x8 __attribute__((ext_vector_type(8)));
typedef float   f32x4  __attribute__((ext_vector_type(4)));

union HU { _Float16 h; ushort u; };
union FU { float f; uint u; };

__device__ __forceinline__ ushort f2bf(float f) {
    FU v; v.f = f;
    return (ushort)((v.u + 0x7fffu + ((v.u >> 16) & 1u)) >> 16);   // RNE
}
__device__ __forceinline__ uint pk(float a, float b) {
    return (uint)f2bf(a) | ((uint)f2bf(b) << 16);
}
__device__ __forceinline__ ushort f2h(float f) { HU h; h.h = (_Float16)f; return h.u; }
__device__ __forceinline__ float  h2f(ushort u) { HU h; h.u = u; return (float)h.h; }
__device__ __forceinline__ float  bflo(uint u) { FU v; v.u = u << 16; return v.f; }
__device__ __forceinline__ float  bfhi(uint u) { FU v; v.u = u & 0xffff0000u; return v.f; }

// ---------------- P: B mats -> bf16 fragment order; cn; accum=0 ----------------
// fragment layout (ushort idx): ((kc*2+mat)*2+ks)*8+ntg)*512 + (quad*16+l16)*8 + j
//   where p = kc*64 + ks*32 + quad*8 + j, f = ntg*16 + l16.
__global__ void k_prep(const float* __restrict__ wgt, const float* __restrict__ ctrl,
                       ushort* __restrict__ wsB, float* __restrict__ cn,
                       float* __restrict__ accum) {
    if (blockIdx.x < 288) {
        int e = blockIdx.x * 256 + threadIdx.x;   // < 73728
        int p = e >> 7, f = e & 127;
        int kc = p >> 6, r = p & 63;
        int ks = r >> 5, quad = (r >> 3) & 3, j = r & 7;
        int ntg = f >> 4, l16 = f & 15;
        int off0 = (((kc * 4 + ks) * 8 + ntg) * 512) + (quad * 16 + l16) * 8 + j;
        wsB[off0]        = f2bf(wgt[e]);    // mat 0
        wsB[off0 + 8192] = f2bf(ctrl[e]);   // mat 1 (+2*8*512)
    } else if (threadIdx.x < 128) {
        int f = threadIdx.x;
        float s = 0.f;
        for (int p = 0; p < P_; ++p) { float v = ctrl[p * F_ + f]; s += v * v; }
        cn[f] = s;
        if (f == 0) accum[0] = 0.f;
    }
}

// ---------------- D: fused dual implicit GEMM ----------------
// 256 threads = 4 waves: w = fh*2 + mat. Each wave: 128 M x 64 F.
// LDS: lI [4][68][64] bf16 (XOR-swizzled, zero-padded) 34816 B |
//      lB 32768 B (one kc, both mats, fragment order) | sArr 1088 B | pnAr 512 B.
__launch_bounds__(256, 2)
__global__ void k_main(const float* __restrict__ in, const ushort* __restrict__ wsB,
                       const float* __restrict__ bias, const float* __restrict__ cn,
                       uint* __restrict__ out, float* __restrict__ accum) {
    __shared__ __attribute__((aligned(16))) ushort smem[34592];   // 69184 B
    ushort* lI   = smem;                        // 17408 ush
    ushort* lB   = smem + 17408;                // 16384 ush
    float*  sArr = (float*)(smem + 33792);      // 272 f32 (stride 68)
    float*  pnAr = (float*)(smem + 34336);      // 128 f32

    const int tid = threadIdx.x;
    const int n0  = blockIdx.x * 128;           // 2 image rows, same image
    const int b   = n0 >> 12;
    const int y0  = (n0 >> 6) & 63;
    const float* inb = in + b * 262144;

    const int w    = tid >> 6, lane = tid & 63;
    const int mat  = w & 1, fh = w >> 1;        // wave = (fh, mat)
    const int quad = lane >> 4, l16 = lane & 15;

    // prefetch B chunk kc=0 (straight copy, fragment order)
    uint4 pb[8];
    #pragma unroll
    for (int i = 0; i < 8; ++i)
        pb[i] = *(const uint4*)&wsB[(tid + i * 256) * 8];

    // ---- stage image tile once: 4 rows x 68 px x 8 chunks = 2176 x 16B
    for (int g = tid; g < 2176; g += 256) {
        int row4 = g / 544;                     // 544 = 68*8
        int rem  = g - row4 * 544;
        int px = rem >> 3, c = rem & 7;
        int y = y0 + row4 - 1, x = px - 1;
        float4 v0 = make_float4(0.f, 0.f, 0.f, 0.f), v1 = v0;
        if (y >= 0 && y < 64 && x >= 0 && x < 64) {
            const float* sp = inb + y * 4096 + x * 64 + c * 8;
            v0 = *(const float4*)sp;
            v1 = *(const float4*)(sp + 4);
        }
        uint4 o = { pk(v0.x, v0.y), pk(v0.z, v0.w), pk(v1.x, v1.y), pk(v1.z, v1.w) };
        *(uint4*)&lI[(row4 * 68 + px) * 64 + ((c ^ (px & 7)) << 3)] = o;
    }
    __syncthreads();

    // ---- s[row4][px] = channel sqnorm of tile pixel (pad pixels -> 0)
    for (int g = tid; g < 264; g += 256) {
        int row4 = g / 66, px = g - row4 * 66;
        const ushort* base = &lI[(row4 * 68 + px) * 64];
        float s = 0.f;
        #pragma unroll
        for (int j = 0; j < 8; ++j) {
            int jj = (j + px) & 7;
            uint4 v = *(const uint4*)&base[jj << 3];
            float a0 = bflo(v.x), a1 = bfhi(v.x), a2 = bflo(v.y), a3 = bfhi(v.y);
            float a4 = bflo(v.z), a5 = bfhi(v.z), a6 = bflo(v.w), a7 = bfhi(v.w);
            s += a0*a0 + a1*a1 + a2*a2 + a3*a3 + a4*a4 + a5*a5 + a6*a6 + a7*a7;
        }
        sArr[row4 * 68 + px] = s;
    }
    __syncthreads();

    // ---- pn[m] = 3x3 box sum (visible to epilogue via later barriers)
    if (tid < 128) {
        int yr = tid >> 6, x = tid & 63;
        float a = 0.f;
        #pragma unroll
        for (int dr = 0; dr < 3; ++dr)
            #pragma unroll
            for (int dc = 0; dc < 3; ++dc)
                a += sArr[(yr + dr) * 68 + x + dc];
        pnAr[tid] = a;
    }

    f32x4 acc[8][4];
    #pragma unroll
    for (int mt = 0; mt < 8; ++mt)
        #pragma unroll
        for (int nt = 0; nt < 4; ++nt)
            acc[mt][nt] = (f32x4){0.f, 0.f, 0.f, 0.f};

    const int lBw = (mat * 16 + fh * 4) * 512 + lane * 8;   // wave B base (ush)

    for (int kc = 0; kc < 9; ++kc) {
        const int ki = kc / 3, kj = kc - 3 * ki;

        __syncthreads();                        // kc-1 readers done
        #pragma unroll
        for (int i = 0; i < 8; ++i)
            *(uint4*)&lB[(tid + i * 256) * 8] = pb[i];
        if (kc < 8) {
            const ushort* src = wsB + (kc + 1) * 16384;
            #pragma unroll
            for (int i = 0; i < 8; ++i)
                pb[i] = *(const uint4*)&src[(tid + i * 256) * 8];   // lands during MFMA
        }
        __syncthreads();

        const int swk = (l16 + kj) & 7;
        #pragma unroll
        for (int ks = 0; ks < 2; ++ks) {
            bf16x8 bfr[4];
            #pragma unroll
            for (int nt = 0; nt < 4; ++nt)
                bfr[nt] = *(const bf16x8*)&lB[lBw + (ks * 8 + nt) * 512];
            const int c  = ks * 4 + quad;
            const int sw = (c ^ swk) << 3;
            #pragma unroll
            for (int mt = 0; mt < 8; ++mt) {
                const int ad = (((mt >> 2) + ki) * 68 + (mt & 3) * 16 + l16 + kj) * 64 + sw;
                bf16x8 a = *(const bf16x8*)&lI[ad];
                #pragma unroll
                for (int nt = 0; nt < 4; ++nt)
                    acc[mt][nt] = __builtin_amdgcn_mfma_f32_16x16x32_bf16(a, bfr[nt], acc[mt][nt], 0, 0, 0);
            }
        }
    }

    // ---- epilogue: C/D layout col=lane&15, row=quad*4+reg [m89/m91]
    // exchange reuses lI: slot per (fh, lane), stride 130 ush (odd word -> no conflicts)
    ushort* exch = smem;
    __syncthreads();
    if (mat == 1) {
        float cv[4];
        #pragma unroll
        for (int nt = 0; nt < 4; ++nt) cv[nt] = cn[fh * 64 + nt * 16 + l16];
        float sum = 0.f;
        ushort* my = exch + (fh * 64 + lane) * 130;
        #pragma unroll
        for (int mt = 0; mt < 8; ++mt) {
            float pv[4];
            #pragma unroll
            for (int r = 0; r < 4; ++r) pv[r] = pnAr[mt * 16 + quad * 4 + r];
            #pragma unroll
            for (int nt = 0; nt < 4; ++nt) {
                float d0 = pv[0] + cv[nt] - 2.f * acc[mt][nt][0];
                float d1 = pv[1] + cv[nt] - 2.f * acc[mt][nt][1];
                float d2 = pv[2] + cv[nt] - 2.f * acc[mt][nt][2];
                float d3 = pv[3] + cv[nt] - 2.f * acc[mt][nt][3];
                sum += d0 + d1 + d2 + d3;
                ushort4 hv = { f2h(d0), f2h(d1), f2h(d2), f2h(d3) };
                *(ushort4*)&my[(mt * 4 + nt) * 4] = hv;
            }
        }
        #pragma unroll
        for (int off = 32; off >= 1; off >>= 1) sum += __shfl_down(sum, off, 64);
        if (lane == 0) atomicAdd(accum, sum);
    }
    __syncthreads();
    if (mat == 0) {
        float bv[4];
        #pragma unroll
        for (int nt = 0; nt < 4; ++nt) bv[nt] = bias[fh * 64 + nt * 16 + l16];
        const ushort* my = exch + (fh * 64 + lane) * 130;
        #pragma unroll
        for (int mt = 0; mt < 8; ++mt) {
            int gmb = n0 + mt * 16 + quad * 4;
            #pragma unroll
            for (int nt = 0; nt < 4; ++nt) {
                int gf = fh * 64 + nt * 16 + l16;
                ushort4 hv = *(const ushort4*)&my[(mt * 4 + nt) * 4];
                ushort dd[4] = { hv.x, hv.y, hv.z, hv.w };
                #pragma unroll
                for (int r = 0; r < 4; ++r) {
                    uint pkv = ((uint)dd[r] << 16) | (uint)f2h(acc[mt][nt][r] + bv[nt]);
                    out[(gmb + r) * F_ + gf] = pkv;
                }
            }
        }
    }
}

// ---------------- E: in-place out = conv + exp(-gamma*d) ----------------
__global__ void k_final(uint* __restrict__ out, const float* __restrict__ accum) {
    int i = blockIdx.x * 256 + threadIdx.x;       // handles elems [8i, 8i+8)
    float g = 0.5f * (float)NF / accum[0];        // gamma = 1/(2*mean)
    uint4* p = (uint4*)out;
    uint4 u0 = p[2 * i], u1 = p[2 * i + 1];
    float4 f0, f1;
    f0.x = h2f((ushort)(u0.x & 0xffff)) + __expf(-g * h2f((ushort)(u0.x >> 16)));
    f0.y = h2f((ushort)(u0.y & 0xffff)) + __expf(-g * h2f((ushort)(u0.y >> 16)));
    f0.z = h2f((ushort)(u0.z & 0xffff)) + __expf(-g * h2f((ushort)(u0.z >> 16)));
    f0.w = h2f((ushort)(u0.w & 0xffff)) + __expf(-g * h2f((ushort)(u0.w >> 16)));
    f1.x = h2f((ushort)(u1.x & 0xffff)) + __expf(-g * h2f((ushort)(u1.x >> 16)));
    f1.y = h2f((ushort)(u1.y & 0xffff)) + __expf(-g * h2f((ushort)(u1.y >> 16)));
    f1.z = h2f((ushort)(u1.z & 0xffff)) + __expf(-g * h2f((ushort)(u1.z >> 16)));
    f1.w = h2f((ushort)(u1.w & 0xffff)) + __expf(-g * h2f((ushort)(u1.w >> 16)));
    float4* q = (float4*)out;
    q[2 * i] = f0; q[2 * i + 1] = f1;             // in-place, same bytes
}

extern "C" void kernel_launch(void* const* d_in, const int* in_sizes, int n_in,
                              void* d_out, int out_size, void* d_ws, size_t ws_size,
                              hipStream_t stream) {
    const float* in   = (const float*)d_in[0];   // [32,64,64,64]
    const float* wgt  = (const float*)d_in[1];   // [3,3,64,128]
    const float* bias = (const float*)d_in[2];   // [128]
    const float* ctrl = (const float*)d_in[3];   // [3,3,64,128]
    uint* out = (uint*)d_out;

    // ws: wsB @0 (294912 B, fragment order) | cn @294912 | accum @295424
    char* ws = (char*)d_ws;
    ushort* wsB   = (ushort*)(ws + 0);
    float*  cn    = (float*) (ws + 294912);
    float*  accum = (float*) (ws + 295424);

    k_prep  <<<289,          256, 0, stream>>>(wgt, ctrl, wsB, cn, accum);
    k_main  <<<NPIX / 128,   256, 0, stream>>>(in, wsB, bias, cn, out, accum);
    k_final <<<NF / 8 / 256, 256, 0, stream>>>(out, accum);
}

// Round 6
// 201.457 us; speedup vs baseline: 1.4870x; 1.1313x over previous
//
#include <hip/hip_runtime.h>

// KANConv2D: out[b,h,w,f] = conv3x3(x,K)[.,f] + exp(-gamma * d[.,f]) + bias[f]
// d = ||patch||^2 + ||c_f||^2 - 2*patch.c_f ; gamma = (N*F)/(2*sum(d))
//
// v6: 3 launches, NO finalize pass.
//   sum(d) = F*Sum(pn) + N*Sum(cn) - 2*Sum_n(p_n . chat), chat = Sum_f c_f —
//   computable without the GEMM. k_gamma does one input pass for the stats;
//   k_main computes gamma inline and writes FINAL fp32 output once.
//   k_main: 256 thr / 4 waves, wave = (mhalf,fhalf) 64Mx64F computing BOTH
//   GEMMs (128 AGPR acc, no exchange). Persistent bf16 image tile (v5,
//   verified); B staged per-kc from fragment-ordered ws via plain copy
//   (NO register prefetch arrays — v3/v5 spill lesson, WRITE_SIZE sentinel).

#define B_ 32
#define H_ 64
#define W_ 64
#define C_ 64
#define F_ 128
#define P_ 576
#define NPIX (B_*H_*W_)          // 131072
#define NF   (NPIX*F_)           // 16777216

typedef __bf16  bf16x8 __attribute__((ext_vector_type(8)));
typedef float   f32x4  __attribute__((ext_vector_type(4)));

union FU { float f; uint u; };

__device__ __forceinline__ ushort f2bf(float f) {
    FU v; v.f = f;
    return (ushort)((v.u + 0x7fffu + ((v.u >> 16) & 1u)) >> 16);   // RNE
}
__device__ __forceinline__ uint pk(float a, float b) {
    return (uint)f2bf(a) | ((uint)f2bf(b) << 16);
}
__device__ __forceinline__ float bflo(uint u) { FU v; v.u = u << 16; return v.f; }
__device__ __forceinline__ float bfhi(uint u) { FU v; v.u = u & 0xffff0000u; return v.f; }

// ---------------- P: wsB fragment order | cn,Scn,zero accum | chat table ----------
// fragment layout (ushort idx): ((kc*4 + mat*2 + ks)*8 + ntg)*512 + (quad*16+l16)*8 + j
//   where p = kc*64 + ks*32 + quad*8 + j, f = ntg*16 + l16.
__global__ void k_prep(const float* __restrict__ wgt, const float* __restrict__ ctrl,
                       ushort* __restrict__ wsB, float* __restrict__ cn,
                       float* __restrict__ accum, float* __restrict__ tab) {
    __shared__ float sh[576];
    if (blockIdx.x < 288) {
        int e = blockIdx.x * 256 + threadIdx.x;   // < 73728
        int p = e >> 7, f = e & 127;
        int kc = p >> 6, r = p & 63;
        int ks = r >> 5, quad = (r >> 3) & 3, j = r & 7;
        int ntg = f >> 4, l16 = f & 15;
        int off0 = (((kc * 4 + ks) * 8 + ntg) * 512) + (quad * 16 + l16) * 8 + j;
        wsB[off0]        = f2bf(wgt[e]);    // mat 0 (kernel)
        wsB[off0 + 8192] = f2bf(ctrl[e]);   // mat 1 (+ mat*2*8*512)
    } else if (blockIdx.x == 288) {
        // cn[f], Scn, zero the two k_gamma accumulators
        int t = threadIdx.x;
        float s = 0.f;
        if (t < 128) {
            for (int p = 0; p < P_; ++p) { float v = ctrl[p * F_ + t]; s += v * v; }
            cn[t] = s;
        }
        #pragma unroll
        for (int off = 32; off >= 1; off >>= 1) s += __shfl_down(s, off, 64);
        if ((t & 63) == 0) sh[t >> 6] = s;
        __syncthreads();
        if (t == 0) {
            accum[0] = 0.f;                  // Sum(w * ||pix||^2) = Sum(pn)
            accum[1] = 0.f;                  // Sum_n p_n . chat
            accum[2] = sh[0] + sh[1];        // Scn
        }
    } else {
        // chat[ki][kj][c] = Sum_f ctrl[ki,kj,c,f]; then 9 border variants
        int t = threadIdx.x;
        for (int e = t; e < 576; e += 256) {
            const float* row = ctrl + e * F_;
            float s = 0.f;
            for (int f = 0; f < F_; ++f) s += row[f];
            sh[e] = s;
        }
        __syncthreads();
        for (int idx = t; idx < 576; idx += 256) {
            int q = idx >> 6, c = idx & 63;     // q = ry*3+rx
            int ry = q / 3, rx = q - 3 * ry;
            int my = (ry == 0) ? 3 : (ry == 2) ? 6 : 7;   // ki bitmask {0,1}/{1,2}/{0,1,2}
            int mx = (rx == 0) ? 3 : (rx == 2) ? 6 : 7;
            float s = 0.f;
            #pragma unroll
            for (int ki = 0; ki < 3; ++ki)
                #pragma unroll
                for (int kj = 0; kj < 3; ++kj)
                    if ((my >> ki & 1) && (mx >> kj & 1))
                        s += sh[(ki * 3 + kj) * 64 + c];
            tab[idx] = s;
        }
    }
}

// ---------------- G: global stats for gamma (one input pass) ----------------
__global__ void k_gamma(const float* __restrict__ in, const float* __restrict__ tab,
                        float* __restrict__ accum) {
    int n = blockIdx.x * 256 + threadIdx.x;    // pixel
    int y = (n >> 6) & 63, x = n & 63;
    int ry = (y == 0) ? 0 : (y == 63) ? 2 : 1;
    int rx = (x == 0) ? 0 : (x == 63) ? 2 : 1;
    const float4* xp = (const float4*)(in + n * 64);
    const float4* tp = (const float4*)(tab + (ry * 3 + rx) * 64);
    float s = 0.f, pc = 0.f;
    #pragma unroll
    for (int i = 0; i < 16; ++i) {
        float4 v = xp[i], t = tp[i];
        s  += v.x * v.x + v.y * v.y + v.z * v.z + v.w * v.w;
        pc += v.x * t.x + v.y * t.y + v.z * t.z + v.w * t.w;
    }
    float wgt = (float)((3 - (y == 0) - (y == 63)) * (3 - (x == 0) - (x == 63)));
    float ws_ = s * wgt;
    #pragma unroll
    for (int off = 32; off >= 1; off >>= 1) {
        ws_ += __shfl_down(ws_, off, 64);
        pc  += __shfl_down(pc,  off, 64);
    }
    if ((threadIdx.x & 63) == 0) {
        atomicAdd(&accum[0], ws_);
        atomicAdd(&accum[1], pc);
    }
}

// ---------------- D: fused dual implicit GEMM + inline gamma epilogue ----------
// 256 threads = 4 waves: w = mhalf*2 + fhalf. Each wave: 64M x 64F, BOTH mats.
// LDS: lI [4][68][64] bf16 (XOR-swizzled, zero-padded) | lB 32 KB (one kc,
//      both mats, fragment order) | sArr [4][68] f32 | pnAr [128] f32.
__launch_bounds__(256, 2)
__global__ void k_main(const float* __restrict__ in, const ushort* __restrict__ wsB,
                       const float* __restrict__ bias, const float* __restrict__ cn,
                       const float* __restrict__ accum, float* __restrict__ out) {
    __shared__ __attribute__((aligned(16))) ushort smem[34592];   // 69184 B
    ushort* lI   = smem;                        // 17408 ush
    ushort* lB   = smem + 17408;                // 16384 ush
    float*  sArr = (float*)(smem + 33792);      // 272 f32 (stride 68)
    float*  pnAr = (float*)(smem + 34336);      // 128 f32

    const int tid = threadIdx.x;
    const int n0  = blockIdx.x * 128;           // 2 image rows, same image
    const int b   = n0 >> 12;
    const int y0  = (n0 >> 6) & 63;
    const float* inb = in + b * 262144;

    const int w     = tid >> 6, lane = tid & 63;
    const int fhalf = w & 1, mhalf = w >> 1;
    const int quad  = lane >> 4, l16 = lane & 15;

    // ---- stage image tile once: 4 rows x 68 px x 8 chunks = 2176 x 16B
    for (int g = tid; g < 2176; g += 256) {
        int row4 = g / 544;                     // 544 = 68*8
        int rem  = g - row4 * 544;
        int px = rem >> 3, c = rem & 7;
        int y = y0 + row4 - 1, x = px - 1;
        float4 v0 = make_float4(0.f, 0.f, 0.f, 0.f), v1 = v0;
        if (y >= 0 && y < 64 && x >= 0 && x < 64) {
            const float* sp = inb + y * 4096 + x * 64 + c * 8;
            v0 = *(const float4*)sp;
            v1 = *(const float4*)(sp + 4);
        }
        uint4 o = { pk(v0.x, v0.y), pk(v0.z, v0.w), pk(v1.x, v1.y), pk(v1.z, v1.w) };
        *(uint4*)&lI[(row4 * 68 + px) * 64 + ((c ^ (px & 7)) << 3)] = o;
    }
    __syncthreads();

    // ---- s[row4][px] = channel sqnorm of tile pixel (pad pixels -> 0)
    for (int g = tid; g < 264; g += 256) {
        int row4 = g / 66, px = g - row4 * 66;
        const ushort* base = &lI[(row4 * 68 + px) * 64];
        float s = 0.f;
        #pragma unroll
        for (int j = 0; j < 8; ++j) {
            int jj = (j + px) & 7;
            uint4 v = *(const uint4*)&base[jj << 3];
            float a0 = bflo(v.x), a1 = bfhi(v.x), a2 = bflo(v.y), a3 = bfhi(v.y);
            float a4 = bflo(v.z), a5 = bfhi(v.z), a6 = bflo(v.w), a7 = bfhi(v.w);
            s += a0*a0 + a1*a1 + a2*a2 + a3*a3 + a4*a4 + a5*a5 + a6*a6 + a7*a7;
        }
        sArr[row4 * 68 + px] = s;
    }
    __syncthreads();

    // ---- pn[m] = 3x3 box sum (consumed in epilogue, after more barriers)
    if (tid < 128) {
        int yr = tid >> 6, x = tid & 63;
        float a = 0.f;
        #pragma unroll
        for (int dr = 0; dr < 3; ++dr)
            #pragma unroll
            for (int dc = 0; dc < 3; ++dc)
                a += sArr[(yr + dr) * 68 + x + dc];
        pnAr[tid] = a;
    }

    f32x4 accW[4][4], accC[4][4];
    #pragma unroll
    for (int mt = 0; mt < 4; ++mt)
        #pragma unroll
        for (int nt = 0; nt < 4; ++nt) {
            accW[mt][nt] = (f32x4){0.f, 0.f, 0.f, 0.f};
            accC[mt][nt] = (f32x4){0.f, 0.f, 0.f, 0.f};
        }

    const int fh4 = fhalf * 4;

    for (int kc = 0; kc < 9; ++kc) {
        const int ki = kc / 3, kj = kc - 3 * ki;

        __syncthreads();                        // kc-1 readers done
        {   // plain copy staging — short-lived temps only (no spill)
            const ushort* src = wsB + kc * 16384;
            #pragma unroll
            for (int i = 0; i < 8; ++i) {
                uint4 v = *(const uint4*)&src[(tid + i * 256) * 8];
                *(uint4*)&lB[(tid + i * 256) * 8] = v;
            }
        }
        __syncthreads();

        const int swk = (l16 + kj) & 7;
        const int rb0 = (mhalf + ki) * 68 + l16 + kj;
        #pragma unroll
        for (int ks = 0; ks < 2; ++ks) {
            bf16x8 bw[4], bc[4];
            #pragma unroll
            for (int nt = 0; nt < 4; ++nt) {
                bw[nt] = *(const bf16x8*)&lB[(ks * 8      + fh4 + nt) * 512 + lane * 8];
                bc[nt] = *(const bf16x8*)&lB[(ks * 8 + 16 + fh4 + nt) * 512 + lane * 8];
            }
            const int c  = ks * 4 + quad;
            const int sw = (c ^ swk) << 3;
            #pragma unroll
            for (int mt = 0; mt < 4; ++mt) {
                bf16x8 a = *(const bf16x8*)&lI[(rb0 + mt * 16) * 64 + sw];
                #pragma unroll
                for (int nt = 0; nt < 4; ++nt) {
                    accW[mt][nt] = __builtin_amdgcn_mfma_f32_16x16x32_bf16(a, bw[nt], accW[mt][nt], 0, 0, 0);
                    accC[mt][nt] = __builtin_amdgcn_mfma_f32_16x16x32_bf16(a, bc[nt], accC[mt][nt], 0, 0, 0);
                }
            }
        }
    }

    // ---- epilogue: gamma inline; C/D layout col=lane&15, row=quad*4+reg [m89/m91]
    float Spn = accum[0], Spc = accum[1], Scn = accum[2];
    float Sd  = 128.f * Spn + 131072.f * Scn - 2.f * Spc;
    float g   = 0.5f * 16777216.f / Sd;
    float bv[4], cv[4];
    #pragma unroll
    for (int nt = 0; nt < 4; ++nt) {
        int gf = fhalf * 64 + nt * 16 + l16;
        bv[nt] = bias[gf];
        cv[nt] = cn[gf];
    }
    #pragma unroll
    for (int mt = 0; mt < 4; ++mt) {
        int rloc = mhalf * 64 + mt * 16 + quad * 4;
        float pv[4];
        #pragma unroll
        for (int r = 0; r < 4; ++r) pv[r] = pnAr[rloc + r];
        int gm = n0 + rloc;
        #pragma unroll
        for (int nt = 0; nt < 4; ++nt) {
            int gf = fhalf * 64 + nt * 16 + l16;
            #pragma unroll
            for (int r = 0; r < 4; ++r) {
                float d = pv[r] + cv[nt] - 2.f * accC[mt][nt][r];
                out[(gm + r) * F_ + gf] = accW[mt][nt][r] + bv[nt] + __expf(-g * d);
            }
        }
    }
}

extern "C" void kernel_launch(void* const* d_in, const int* in_sizes, int n_in,
                              void* d_out, int out_size, void* d_ws, size_t ws_size,
                              hipStream_t stream) {
    const float* in   = (const float*)d_in[0];   // [32,64,64,64]
    const float* wgt  = (const float*)d_in[1];   // [3,3,64,128]
    const float* bias = (const float*)d_in[2];   // [128]
    const float* ctrl = (const float*)d_in[3];   // [3,3,64,128]
    float* out = (float*)d_out;

    // ws: wsB @0 (294912 B) | cn @294912 (512) | accum @295424 (3 f32) | tab @295440 (2304)
    char* ws = (char*)d_ws;
    ushort* wsB   = (ushort*)(ws + 0);
    float*  cn    = (float*) (ws + 294912);
    float*  accum = (float*) (ws + 295424);
    float*  tab   = (float*) (ws + 295440);

    k_prep  <<<290,        256, 0, stream>>>(wgt, ctrl, wsB, cn, accum, tab);
    k_gamma <<<NPIX / 256, 256, 0, stream>>>(in, tab, accum);
    k_main  <<<NPIX / 128, 256, 0, stream>>>(in, wsB, bias, cn, accum, out);
}

// Round 7
// 155.053 us; speedup vs baseline: 1.9320x; 1.2993x over previous
//
#include <hip/hip_runtime.h>

// KANConv2D: out[b,h,w,f] = conv3x3(x,K)[.,f] + exp(-gamma * d[.,f]) + bias[f]
// d = ||patch||^2 + ||c_f||^2 - 2*patch.c_f ; gamma = (N*F)/(2*sum(d))
//
// v7: identical to v6 except k_gamma rebuilt:
//  - coalesced: 16-lane group per pixel (lane seg reads in[pix*64+seg*4]),
//    256 contiguous pixels per block (v6 was 256B-strided per lane -> 64-way
//    transaction splintering)
//  - one atomic pair per BLOCK (LDS-reduced), accumulators on separate cache
//    lines (v6: 4096 same-line fp32 atomics = the 61us)
//   sum(d) = F*Sum(pn) + N*Sum(cn) - 2*Sum_n(p_n . chat), chat = Sum_f c_f.
//   k_main: 256 thr / 4 waves, wave = (mhalf,fhalf) 64Mx64F computing BOTH
//   GEMMs (128 AGPR acc, no exchange); persistent bf16 image tile; B staged
//   per-kc from fragment-ordered ws via plain copy (no prefetch regs — spill).

#define B_ 32
#define H_ 64
#define W_ 64
#define C_ 64
#define F_ 128
#define P_ 576
#define NPIX (B_*H_*W_)          // 131072
#define NF   (NPIX*F_)           // 16777216

typedef __bf16  bf16x8 __attribute__((ext_vector_type(8)));
typedef float   f32x4  __attribute__((ext_vector_type(4)));

union FU { float f; uint u; };

__device__ __forceinline__ ushort f2bf(float f) {
    FU v; v.f = f;
    return (ushort)((v.u + 0x7fffu + ((v.u >> 16) & 1u)) >> 16);   // RNE
}
__device__ __forceinline__ uint pk(float a, float b) {
    return (uint)f2bf(a) | ((uint)f2bf(b) << 16);
}
__device__ __forceinline__ float bflo(uint u) { FU v; v.u = u << 16; return v.f; }
__device__ __forceinline__ float bfhi(uint u) { FU v; v.u = u & 0xffff0000u; return v.f; }

// accum slots (separate cache lines): [0]=Sum(pn), [16]=Sum(p.chat), [32]=Sum(cn)
#define ACC_SPN 0
#define ACC_SPC 16
#define ACC_SCN 32

// ---------------- P: wsB fragment order | cn,Scn,zero accum | chat table ----------
// fragment layout (ushort idx): ((kc*4 + mat*2 + ks)*8 + ntg)*512 + (quad*16+l16)*8 + j
//   where p = kc*64 + ks*32 + quad*8 + j, f = ntg*16 + l16.
__global__ void k_prep(const float* __restrict__ wgt, const float* __restrict__ ctrl,
                       ushort* __restrict__ wsB, float* __restrict__ cn,
                       float* __restrict__ accum, float* __restrict__ tab) {
    __shared__ float sh[576];
    if (blockIdx.x < 288) {
        int e = blockIdx.x * 256 + threadIdx.x;   // < 73728
        int p = e >> 7, f = e & 127;
        int kc = p >> 6, r = p & 63;
        int ks = r >> 5, quad = (r >> 3) & 3, j = r & 7;
        int ntg = f >> 4, l16 = f & 15;
        int off0 = (((kc * 4 + ks) * 8 + ntg) * 512) + (quad * 16 + l16) * 8 + j;
        wsB[off0]        = f2bf(wgt[e]);    // mat 0 (kernel)
        wsB[off0 + 8192] = f2bf(ctrl[e]);   // mat 1 (+ mat*2*8*512)
    } else if (blockIdx.x == 288) {
        // cn[f], Scn, zero the two k_gamma accumulators
        int t = threadIdx.x;
        float s = 0.f;
        if (t < 128) {
            for (int p = 0; p < P_; ++p) { float v = ctrl[p * F_ + t]; s += v * v; }
            cn[t] = s;
        }
        #pragma unroll
        for (int off = 32; off >= 1; off >>= 1) s += __shfl_down(s, off, 64);
        if ((t & 63) == 0) sh[t >> 6] = s;
        __syncthreads();
        if (t == 0) {
            accum[ACC_SPN] = 0.f;
            accum[ACC_SPC] = 0.f;
            accum[ACC_SCN] = sh[0] + sh[1];
        }
    } else {
        // chat[ki][kj][c] = Sum_f ctrl[ki,kj,c,f]; then 9 border variants
        int t = threadIdx.x;
        for (int e = t; e < 576; e += 256) {
            const float* row = ctrl + e * F_;
            float s = 0.f;
            for (int f = 0; f < F_; ++f) s += row[f];
            sh[e] = s;
        }
        __syncthreads();
        for (int idx = t; idx < 576; idx += 256) {
            int q = idx >> 6, c = idx & 63;     // q = ry*3+rx
            int ry = q / 3, rx = q - 3 * ry;
            int my = (ry == 0) ? 3 : (ry == 2) ? 6 : 7;   // valid-ki bitmask
            int mx = (rx == 0) ? 3 : (rx == 2) ? 6 : 7;
            float s = 0.f;
            #pragma unroll
            for (int ki = 0; ki < 3; ++ki)
                #pragma unroll
                for (int kj = 0; kj < 3; ++kj)
                    if ((my >> ki & 1) && (mx >> kj & 1))
                        s += sh[(ki * 3 + kj) * 64 + c];
            tab[idx] = s;
        }
    }
}

// ---------------- G: global stats for gamma (one coalesced input pass) ----------
// 256 thr: 16-lane group per pixel, 16 pixels/step, 16 steps = 256 px/block.
__launch_bounds__(256)
__global__ void k_gamma(const float* __restrict__ in, const float* __restrict__ tab,
                        float* __restrict__ accum) {
    __shared__ float shs[4], shp[4];
    const int t = threadIdx.x, seg = t & 15, grp = t >> 4;
    float s = 0.f, pc = 0.f;
    #pragma unroll 4
    for (int it = 0; it < 16; ++it) {
        int pix = blockIdx.x * 256 + it * 16 + grp;
        int y = (pix >> 6) & 63, x = pix & 63;
        float4 v = *((const float4*)(in + pix * 64) + seg);
        int ry = (y == 0) ? 0 : (y == 63) ? 2 : 1;
        int rx = (x == 0) ? 0 : (x == 63) ? 2 : 1;
        float4 tv = *((const float4*)(tab + (ry * 3 + rx) * 64) + seg);
        float wq = (float)((3 - (y == 0) - (y == 63)) * (3 - (x == 0) - (x == 63)));
        s  += wq * (v.x*v.x + v.y*v.y + v.z*v.z + v.w*v.w);
        pc += v.x*tv.x + v.y*tv.y + v.z*tv.z + v.w*tv.w;
    }
    #pragma unroll
    for (int off = 32; off >= 1; off >>= 1) {
        s  += __shfl_down(s,  off, 64);
        pc += __shfl_down(pc, off, 64);
    }
    if ((t & 63) == 0) { shs[t >> 6] = s; shp[t >> 6] = pc; }
    __syncthreads();
    if (t == 0) atomicAdd(&accum[ACC_SPN], shs[0] + shs[1] + shs[2] + shs[3]);
    if (t == 64) atomicAdd(&accum[ACC_SPC], shp[0] + shp[1] + shp[2] + shp[3]);
}

// ---------------- D: fused dual implicit GEMM + inline gamma epilogue ----------
// 256 threads = 4 waves: w = mhalf*2 + fhalf. Each wave: 64M x 64F, BOTH mats.
// LDS: lI [4][68][64] bf16 (XOR-swizzled, zero-padded) | lB 32 KB (one kc,
//      both mats, fragment order) | sArr [4][68] f32 | pnAr [128] f32.
__launch_bounds__(256, 2)
__global__ void k_main(const float* __restrict__ in, const ushort* __restrict__ wsB,
                       const float* __restrict__ bias, const float* __restrict__ cn,
                       const float* __restrict__ accum, float* __restrict__ out) {
    __shared__ __attribute__((aligned(16))) ushort smem[34592];   // 69184 B
    ushort* lI   = smem;                        // 17408 ush
    ushort* lB   = smem + 17408;                // 16384 ush
    float*  sArr = (float*)(smem + 33792);      // 272 f32 (stride 68)
    float*  pnAr = (float*)(smem + 34336);      // 128 f32

    const int tid = threadIdx.x;
    const int n0  = blockIdx.x * 128;           // 2 image rows, same image
    const int b   = n0 >> 12;
    const int y0  = (n0 >> 6) & 63;
    const float* inb = in + b * 262144;

    const int w     = tid >> 6, lane = tid & 63;
    const int fhalf = w & 1, mhalf = w >> 1;
    const int quad  = lane >> 4, l16 = lane & 15;

    // ---- stage image tile once: 4 rows x 68 px x 8 chunks = 2176 x 16B
    for (int g = tid; g < 2176; g += 256) {
        int row4 = g / 544;                     // 544 = 68*8
        int rem  = g - row4 * 544;
        int px = rem >> 3, c = rem & 7;
        int y = y0 + row4 - 1, x = px - 1;
        float4 v0 = make_float4(0.f, 0.f, 0.f, 0.f), v1 = v0;
        if (y >= 0 && y < 64 && x >= 0 && x < 64) {
            const float* sp = inb + y * 4096 + x * 64 + c * 8;
            v0 = *(const float4*)sp;
            v1 = *(const float4*)(sp + 4);
        }
        uint4 o = { pk(v0.x, v0.y), pk(v0.z, v0.w), pk(v1.x, v1.y), pk(v1.z, v1.w) };
        *(uint4*)&lI[(row4 * 68 + px) * 64 + ((c ^ (px & 7)) << 3)] = o;
    }
    __syncthreads();

    // ---- s[row4][px] = channel sqnorm of tile pixel (pad pixels -> 0)
    for (int g = tid; g < 264; g += 256) {
        int row4 = g / 66, px = g - row4 * 66;
        const ushort* base = &lI[(row4 * 68 + px) * 64];
        float s = 0.f;
        #pragma unroll
        for (int j = 0; j < 8; ++j) {
            int jj = (j + px) & 7;
            uint4 v = *(const uint4*)&base[jj << 3];
            float a0 = bflo(v.x), a1 = bfhi(v.x), a2 = bflo(v.y), a3 = bfhi(v.y);
            float a4 = bflo(v.z), a5 = bfhi(v.z), a6 = bflo(v.w), a7 = bfhi(v.w);
            s += a0*a0 + a1*a1 + a2*a2 + a3*a3 + a4*a4 + a5*a5 + a6*a6 + a7*a7;
        }
        sArr[row4 * 68 + px] = s;
    }
    __syncthreads();

    // ---- pn[m] = 3x3 box sum (consumed in epilogue, after more barriers)
    if (tid < 128) {
        int yr = tid >> 6, x = tid & 63;
        float a = 0.f;
        #pragma unroll
        for (int dr = 0; dr < 3; ++dr)
            #pragma unroll
            for (int dc = 0; dc < 3; ++dc)
                a += sArr[(yr + dr) * 68 + x + dc];
        pnAr[tid] = a;
    }

    f32x4 accW[4][4], accC[4][4];
    #pragma unroll
    for (int mt = 0; mt < 4; ++mt)
        #pragma unroll
        for (int nt = 0; nt < 4; ++nt) {
            accW[mt][nt] = (f32x4){0.f, 0.f, 0.f, 0.f};
            accC[mt][nt] = (f32x4){0.f, 0.f, 0.f, 0.f};
        }

    const int fh4 = fhalf * 4;

    for (int kc = 0; kc < 9; ++kc) {
        const int ki = kc / 3, kj = kc - 3 * ki;

        __syncthreads();                        // kc-1 readers done
        {   // plain copy staging — short-lived temps only (no spill)
            const ushort* src = wsB + kc * 16384;
            #pragma unroll
            for (int i = 0; i < 8; ++i) {
                uint4 v = *(const uint4*)&src[(tid + i * 256) * 8];
                *(uint4*)&lB[(tid + i * 256) * 8] = v;
            }
        }
        __syncthreads();

        const int swk = (l16 + kj) & 7;
        const int rb0 = (mhalf + ki) * 68 + l16 + kj;
        #pragma unroll
        for (int ks = 0; ks < 2; ++ks) {
            bf16x8 bw[4], bc[4];
            #pragma unroll
            for (int nt = 0; nt < 4; ++nt) {
                bw[nt] = *(const bf16x8*)&lB[(ks * 8      + fh4 + nt) * 512 + lane * 8];
                bc[nt] = *(const bf16x8*)&lB[(ks * 8 + 16 + fh4 + nt) * 512 + lane * 8];
            }
            const int c  = ks * 4 + quad;
            const int sw = (c ^ swk) << 3;
            #pragma unroll
            for (int mt = 0; mt < 4; ++mt) {
                bf16x8 a = *(const bf16x8*)&lI[(rb0 + mt * 16) * 64 + sw];
                #pragma unroll
                for (int nt = 0; nt < 4; ++nt) {
                    accW[mt][nt] = __builtin_amdgcn_mfma_f32_16x16x32_bf16(a, bw[nt], accW[mt][nt], 0, 0, 0);
                    accC[mt][nt] = __builtin_amdgcn_mfma_f32_16x16x32_bf16(a, bc[nt], accC[mt][nt], 0, 0, 0);
                }
            }
        }
    }

    // ---- epilogue: gamma inline; C/D layout col=lane&15, row=quad*4+reg [m89/m91]
    float Spn = accum[ACC_SPN], Spc = accum[ACC_SPC], Scn = accum[ACC_SCN];
    float Sd  = 128.f * Spn + 131072.f * Scn - 2.f * Spc;
    float g   = 0.5f * 16777216.f / Sd;
    float bv[4], cv[4];
    #pragma unroll
    for (int nt = 0; nt < 4; ++nt) {
        int gf = fhalf * 64 + nt * 16 + l16;
        bv[nt] = bias[gf];
        cv[nt] = cn[gf];
    }
    #pragma unroll
    for (int mt = 0; mt < 4; ++mt) {
        int rloc = mhalf * 64 + mt * 16 + quad * 4;
        float pv[4];
        #pragma unroll
        for (int r = 0; r < 4; ++r) pv[r] = pnAr[rloc + r];
        int gm = n0 + rloc;
        #pragma unroll
        for (int nt = 0; nt < 4; ++nt) {
            int gf = fhalf * 64 + nt * 16 + l16;
            #pragma unroll
            for (int r = 0; r < 4; ++r) {
                float d = pv[r] + cv[nt] - 2.f * accC[mt][nt][r];
                out[(gm + r) * F_ + gf] = accW[mt][nt][r] + bv[nt] + __expf(-g * d);
            }
        }
    }
}

extern "C" void kernel_launch(void* const* d_in, const int* in_sizes, int n_in,
                              void* d_out, int out_size, void* d_ws, size_t ws_size,
                              hipStream_t stream) {
    const float* in   = (const float*)d_in[0];   // [32,64,64,64]
    const float* wgt  = (const float*)d_in[1];   // [3,3,64,128]
    const float* bias = (const float*)d_in[2];   // [128]
    const float* ctrl = (const float*)d_in[3];   // [3,3,64,128]
    float* out = (float*)d_out;

    // ws: wsB @0 (294912 B) | cn @294912 (512 B) | accum @295424 (192 B, 3 lines)
    //     | tab @295616 (2304 B)
    char* ws = (char*)d_ws;
    ushort* wsB   = (ushort*)(ws + 0);
    float*  cn    = (float*) (ws + 294912);
    float*  accum = (float*) (ws + 295424);
    float*  tab   = (float*) (ws + 295616);

    k_prep  <<<290,        256, 0, stream>>>(wgt, ctrl, wsB, cn, accum, tab);
    k_gamma <<<NPIX / 256, 256, 0, stream>>>(in, tab, accum);
    k_main  <<<NPIX / 128, 256, 0, stream>>>(in, wsB, bias, cn, accum, out);
}